// Round 1
// baseline (138.155 us; speedup 1.0000x reference)
//
#include <hip/hip_runtime.h>

// CRF log-likelihood: mean_b( logZ_b - seq_score_b )
// B=16, T=2048, K=16. Log-semiring matrix-chain reduction, chunked:
//   stage1: B*NC blocks, each computes product of CL=T/NC consecutive KxK matrices
//   stage2: B blocks, each reduces its NC chunk matrices sequentially, computes
//           logZ (row 0 + end_transitions, logsumexp) and the tag-sequence score
//   final : mean over B
#define BB 16
#define TT 2048
#define KK 16
#define NC 64
#define CL 32   // TT / NC

__global__ __launch_bounds__(256) void crf_stage1(
    const float* __restrict__ em, const float* __restrict__ trans,
    const float* __restrict__ startT, float* __restrict__ chunkP)
{
    int blk = blockIdx.x;
    int b = blk >> 6;          // / NC
    int c = blk & (NC - 1);    // % NC
    int tid = threadIdx.x;
    int i = tid >> 4, k = tid & 15;

    __shared__ float P[KK][KK];   // current left product
    // column k of transitions, kept in registers
    float tcol[KK];
#pragma unroll
    for (int j = 0; j < KK; ++j) tcol[j] = trans[j * KK + k];

    int t0 = c * CL;
    const float* emB = em + ((size_t)b * TT + t0) * KK;

    float cur;
    if (c == 0) cur = startT[k] + emB[k];          // "first" matrix: rows identical
    else        cur = trans[i * KK + k] + emB[k];  // transfer matrix at t0
    P[i][k] = cur;
    __syncthreads();

    for (int t = 1; t < CL; ++t) {
        float e = emB[t * KK + k];
        float a[KK];
        float m = -1e30f;
#pragma unroll
        for (int j = 0; j < KK; ++j) {
            a[j] = P[i][j] + tcol[j];   // P row i (LDS broadcast) + trans col k (regs)
            m = fmaxf(m, a[j]);
        }
        float s = 0.f;
#pragma unroll
        for (int j = 0; j < KK; ++j) s += __expf(a[j] - m);
        cur = m + __logf(s) + e;
        __syncthreads();
        P[i][k] = cur;
        __syncthreads();
    }
    chunkP[(size_t)blk * 256 + tid] = cur;
}

__global__ __launch_bounds__(256) void crf_stage2(
    const float* __restrict__ chunkP, const float* __restrict__ em,
    const int* __restrict__ tags, const float* __restrict__ trans,
    const float* __restrict__ startT, const float* __restrict__ endT,
    float* __restrict__ perb)
{
    int b = blockIdx.x;
    int tid = threadIdx.x;
    int i = tid >> 4, k = tid & 15;

    __shared__ float P[KK][KK];
    __shared__ float M[KK][KK];
    __shared__ float s_logZ;
    __shared__ float red[4];

    const float* base = chunkP + (size_t)b * NC * 256;
    P[i][k] = base[tid];
    __syncthreads();

    for (int c = 1; c < NC; ++c) {
        M[i][k] = base[(size_t)c * 256 + tid];
        __syncthreads();
        float a[KK];
        float m = -1e30f;
#pragma unroll
        for (int j = 0; j < KK; ++j) {
            a[j] = P[i][j] + M[j][k];
            m = fmaxf(m, a[j]);
        }
        float s = 0.f;
#pragma unroll
        for (int j = 0; j < KK; ++j) s += __expf(a[j] - m);
        float np = m + __logf(s);
        __syncthreads();
        P[i][k] = np;
        __syncthreads();
    }

    // logZ_b = logsumexp_k( P[0][k] + end[k] )
    if (tid < 16) {
        float fv = P[0][tid] + endT[tid];
        float m = fv;
#pragma unroll
        for (int off = 8; off; off >>= 1) m = fmaxf(m, __shfl_xor(m, off, 16));
        float s = __expf(fv - m);
#pragma unroll
        for (int off = 8; off; off >>= 1) s += __shfl_xor(s, off, 16);
        if (tid == 0) s_logZ = m + __logf(s);
    }

    // tag-sequence score
    const int* tg = tags + (size_t)b * TT;
    const float* emB = em + (size_t)b * TT * KK;
    float part = 0.f;
    for (int t = tid; t < TT; t += 256) {
        int cu = tg[t];
        part += emB[t * KK + cu];
        if (t + 1 < TT) part += trans[cu * KK + tg[t + 1]];
    }
    if (tid == 0) part += startT[tg[0]] + endT[tg[TT - 1]];
#pragma unroll
    for (int off = 32; off; off >>= 1) part += __shfl_xor(part, off, 64);
    if ((tid & 63) == 0) red[tid >> 6] = part;
    __syncthreads();
    if (tid == 0) {
        float ss = red[0] + red[1] + red[2] + red[3];
        perb[b] = s_logZ - ss;
    }
}

__global__ void crf_final(const float* __restrict__ perb, float* __restrict__ out)
{
    int tid = threadIdx.x;
    float v = (tid < BB) ? perb[tid] : 0.f;
#pragma unroll
    for (int off = 32; off; off >>= 1) v += __shfl_xor(v, off, 64);
    if (tid == 0) out[0] = v * (1.f / BB);
}

extern "C" void kernel_launch(void* const* d_in, const int* in_sizes, int n_in,
                              void* d_out, int out_size, void* d_ws, size_t ws_size,
                              hipStream_t stream)
{
    const float* em     = (const float*)d_in[0];
    const int*   tags   = (const int*)d_in[1];
    const float* trans  = (const float*)d_in[2];
    const float* startT = (const float*)d_in[3];
    const float* endT   = (const float*)d_in[4];
    float* out = (float*)d_out;

    float* chunkP = (float*)d_ws;                       // B*NC*256 floats = 1 MiB
    float* perb   = chunkP + (size_t)BB * NC * 256;     // 16 floats

    crf_stage1<<<BB * NC, 256, 0, stream>>>(em, trans, startT, chunkP);
    crf_stage2<<<BB, 256, 0, stream>>>(chunkP, em, tags, trans, startT, endT, perb);
    crf_final<<<1, 64, 0, stream>>>(perb, out);
}

// Round 2
// 97.393 us; speedup vs baseline: 1.4185x; 1.4185x over previous
//
#include <hip/hip_runtime.h>

// CRF log-likelihood: mean_b( logZ_b - seq_score_b )
// B=16, T=2048, K=16.
// Log-semiring matrix chain, 3-level tree, barrier-free recurrences:
//   stage1: B*NC blocks; each computes the product of CL consecutive KxK
//           transfer matrices. Row i of the product is owned by a 16-lane
//           subgroup; cross-lane row broadcast via __shfl(width=16). No LDS.
//   stage2: B*8 blocks; each folds 8 chunk matrices (matrix x matrix, lanes
//           hold one output element, column of next matrix loaded contiguously
//           from transposed storage). Also computes tag-seq score partials.
//   stage3: 1 block; per batch a 16-lane group runs the row-0 VECTOR chain
//           over the 8 stage2 matrices, then logsumexp + mean.
#define BB 16
#define TT 2048
#define KK 16
#define NC 64
#define CL 32   // TT / NC

__global__ __launch_bounds__(256) void crf_stage1(
    const float* __restrict__ em, const float* __restrict__ trans,
    const float* __restrict__ startT, float* __restrict__ chunkT)
{
    int blk = blockIdx.x;
    int b = blk >> 6;          // / NC
    int c = blk & (NC - 1);    // % NC
    int tid = threadIdx.x;
    int i = tid >> 4, k = tid & 15;

    float tcol[KK];            // column k of transitions
#pragma unroll
    for (int j = 0; j < KK; ++j) tcol[j] = trans[j * KK + k];

    const float* emB = em + ((size_t)b * TT + c * CL) * KK;

    float cur = (c == 0 ? startT[k] : trans[i * KK + k]) + emB[k];

    float e_next = emB[KK + k];              // prefetch t=1 emission
#pragma unroll 4
    for (int t = 1; t < CL; ++t) {
        float e = e_next;
        if (t + 1 < CL) e_next = emB[(t + 1) * KK + k];
        float a[KK];
#pragma unroll
        for (int j = 0; j < KK; ++j)
            a[j] = __shfl(cur, j, 16) + tcol[j];   // row i broadcast, no barrier
        float m = a[0];
#pragma unroll
        for (int j = 1; j < KK; ++j) m = fmaxf(m, a[j]);
        float s = 0.f;
#pragma unroll
        for (int j = 0; j < KK; ++j) s += __expf(a[j] - m);
        cur = m + __logf(s) + e;
    }
    // store transposed: chunkT[blk][k][i] so stage2 reads columns contiguously
    chunkT[(size_t)blk * 256 + k * KK + i] = cur;
}

__global__ __launch_bounds__(256) void crf_stage2(
    const float* __restrict__ chunkT, const float* __restrict__ em,
    const int* __restrict__ tags, const float* __restrict__ trans,
    const float* __restrict__ startT, const float* __restrict__ endT,
    float* __restrict__ out2T, float* __restrict__ seqp)
{
    int blk = blockIdx.x;        // 128 blocks
    int b = blk >> 3;            // batch
    int g = blk & 7;             // group of 8 chunks
    int tid = threadIdx.x;
    int i = tid >> 4, k = tid & 15;

    const float* base = chunkT + ((size_t)(b * NC + g * 8)) * 256;
    float cur = base[k * KK + i];            // C_{g*8}[i][k]

#pragma unroll
    for (int c = 1; c < 8; ++c) {
        const float* mp = base + c * 256 + k * KK;   // column k, contiguous
        float mc[KK];
#pragma unroll
        for (int j = 0; j < KK; ++j) mc[j] = mp[j];
        float a[KK];
#pragma unroll
        for (int j = 0; j < KK; ++j)
            a[j] = __shfl(cur, j, 16) + mc[j];
        float m = a[0];
#pragma unroll
        for (int j = 1; j < KK; ++j) m = fmaxf(m, a[j]);
        float s = 0.f;
#pragma unroll
        for (int j = 0; j < KK; ++j) s += __expf(a[j] - m);
        cur = m + __logf(s);
    }
    out2T[(size_t)blk * 256 + k * KK + i] = cur;

    // ---- tag-sequence score partial: this block covers t in [g*256, g*256+256)
    int t = g * 256 + tid;
    const int* tg = tags + (size_t)b * TT;
    int cu = tg[t];
    float part = em[((size_t)b * TT + t) * KK + cu];
    if (t + 1 < TT) part += trans[cu * KK + tg[t + 1]];
    if (t == 0) part += startT[cu];
    if (t == TT - 1) part += endT[cu];
#pragma unroll
    for (int off = 32; off; off >>= 1) part += __shfl_xor(part, off, 64);
    __shared__ float red[4];
    if ((tid & 63) == 0) red[tid >> 6] = part;
    __syncthreads();
    if (tid == 0) seqp[blk] = red[0] + red[1] + red[2] + red[3];
}

__global__ __launch_bounds__(256) void crf_stage3(
    const float* __restrict__ out2T, const float* __restrict__ seqp,
    const float* __restrict__ endT, float* __restrict__ out)
{
    int tid = threadIdx.x;
    int b = tid >> 4, k = tid & 15;   // 16 batches x 16 lanes

    const float* base = out2T + (size_t)b * 8 * 256;
    float v = base[k * KK + 0];       // row 0 of G_0, col k (transposed storage)
#pragma unroll
    for (int g = 1; g < 8; ++g) {
        const float* mp = base + g * 256 + k * KK;
        float mc[KK];
#pragma unroll
        for (int j = 0; j < KK; ++j) mc[j] = mp[j];
        float a[KK];
#pragma unroll
        for (int j = 0; j < KK; ++j)
            a[j] = __shfl(v, j, 16) + mc[j];
        float m = a[0];
#pragma unroll
        for (int j = 1; j < KK; ++j) m = fmaxf(m, a[j]);
        float s = 0.f;
#pragma unroll
        for (int j = 0; j < KK; ++j) s += __expf(a[j] - m);
        v = m + __logf(s);
    }
    float fv = v + endT[k];
    float m = fv;
#pragma unroll
    for (int off = 8; off; off >>= 1) m = fmaxf(m, __shfl_xor(m, off, 16));
    float s = __expf(fv - m);
#pragma unroll
    for (int off = 8; off; off >>= 1) s += __shfl_xor(s, off, 16);
    float logZ = m + __logf(s);                 // uniform within the 16-group

    float sq = (k < 8) ? seqp[b * 8 + k] : 0.f;
#pragma unroll
    for (int off = 8; off; off >>= 1) sq += __shfl_xor(sq, off, 16);

    __shared__ float red[BB];
    if (k == 0) red[b] = logZ - sq;
    __syncthreads();
    if (tid == 0) {
        float acc = 0.f;
#pragma unroll
        for (int bb = 0; bb < BB; ++bb) acc += red[bb];
        out[0] = acc * (1.f / BB);
    }
}

extern "C" void kernel_launch(void* const* d_in, const int* in_sizes, int n_in,
                              void* d_out, int out_size, void* d_ws, size_t ws_size,
                              hipStream_t stream)
{
    const float* em     = (const float*)d_in[0];
    const int*   tags   = (const int*)d_in[1];
    const float* trans  = (const float*)d_in[2];
    const float* startT = (const float*)d_in[3];
    const float* endT   = (const float*)d_in[4];
    float* out = (float*)d_out;

    float* chunkT = (float*)d_ws;                          // 16*64*256 f = 1 MiB
    float* out2T  = chunkT + (size_t)BB * NC * 256;        // 128*256 f = 128 KiB
    float* seqp   = out2T + 128 * 256;                     // 128 f

    crf_stage1<<<BB * NC, 256, 0, stream>>>(em, trans, startT, chunkT);
    crf_stage2<<<BB * 8, 256, 0, stream>>>(chunkT, em, tags, trans, startT, endT,
                                           out2T, seqp);
    crf_stage3<<<1, 256, 0, stream>>>(out2T, seqp, endT, out);
}